// Round 1
// baseline (2063.694 us; speedup 1.0000x reference)
//
#include <hip/hip_runtime.h>
#include <hip/hip_bf16.h>

// Problem constants (from reference setup_inputs)
#define N_BATCH 2
#define C_DIM   768
#define S_DIM   4096
#define L_DIM   1024
#define H_DIM   8
#define D_DIM   96      // C/H
#define TC_DIM  384
#define F_DIM   1536    // 2*C

// ---------------------------------------------------------------------------
// Generic tiled f32 GEMM:  C[b] = op(A @ B[b]) (+ RES[b])
// A: M x K row-major (shared across batch). B: K x N row-major, batch stride sB.
// C: M x N row-major, batch stride sC. RES (optional) same layout as C.
// Tile 64x64, BK=16, 256 threads, 4x4 micro-tile per thread.
// ---------------------------------------------------------------------------
template<bool RELU, bool ADD>
__global__ __launch_bounds__(256) void gemm_f32(
    const float* __restrict__ A, const float* __restrict__ B,
    const float* __restrict__ RES, float* __restrict__ C,
    int M, int N, int K, long sB, long sC)
{
    __shared__ __align__(16) float As[16][68];   // [k][m], padded
    __shared__ __align__(16) float Bs[16][68];   // [k][n], padded
    const int b  = blockIdx.z;
    const float* Bp = B + (long)b * sB;
    float*       Cp = C + (long)b * sC;
    const int m0 = blockIdx.y * 64, n0 = blockIdx.x * 64;
    const int tid = threadIdx.x;
    const int tx = tid & 15, ty = tid >> 4;

    float acc[4][4] = {};

    for (int k0 = 0; k0 < K; k0 += 16) {
        // A tile: 64 rows x 16 k  -> As[k][m] (transposed store)
        #pragma unroll
        for (int i = 0; i < 4; i++) {
            int idx = tid + i * 256;
            int r = idx >> 4, c = idx & 15;
            As[c][r] = A[(long)(m0 + r) * K + (k0 + c)];
        }
        // B tile: 16 k x 64 n
        #pragma unroll
        for (int i = 0; i < 4; i++) {
            int idx = tid + i * 256;
            int r = idx >> 6, c = idx & 63;
            Bs[r][c] = Bp[(long)(k0 + r) * N + (n0 + c)];
        }
        __syncthreads();
        #pragma unroll
        for (int kk = 0; kk < 16; kk++) {
            float a[4], bb[4];
            *(float4*)a  = *(const float4*)&As[kk][ty * 4];
            *(float4*)bb = *(const float4*)&Bs[kk][tx * 4];
            #pragma unroll
            for (int i = 0; i < 4; i++)
                #pragma unroll
                for (int j = 0; j < 4; j++)
                    acc[i][j] = fmaf(a[i], bb[j], acc[i][j]);
        }
        __syncthreads();
    }

    #pragma unroll
    for (int i = 0; i < 4; i++) {
        long r = m0 + ty * 4 + i;
        #pragma unroll
        for (int j = 0; j < 4; j++) {
            long cc = n0 + tx * 4 + j;
            float vv = acc[i][j];
            if (RELU) vv = fmaxf(vv, 0.0f);
            if (ADD)  vv += RES[(long)b * sC + r * N + cc];
            Cp[r * N + cc] = vv;
        }
    }
}

// ---------------------------------------------------------------------------
// Fused attention: per block = one (n, h) x 16 s-rows.
//   coef[s,l] = (q[s,:]·k[:,l]) / sqrt(96) * im[s]
//   proj_out  = coef * tm[l]
//   denom[s]  = sum_l exp(coef)*tm[l] + 1e-6
//   x_p[d,s]  = sum_l exp(coef) * tm[l]^3 * v[d,l] / denom[s]
//   y = x + x_p
// ---------------------------------------------------------------------------
__global__ __launch_bounds__(256) void attn_fused(
    const float* __restrict__ q,   // (N, C, S)
    const float* __restrict__ k,   // (N, C, L)
    const float* __restrict__ v,   // (N, C, L)
    const float* __restrict__ x,   // (N, C, S)
    const float* __restrict__ tmask,  // (N, L)
    const float* __restrict__ imask,  // (N, S)
    float* __restrict__ proj,      // (N, H, S, L)
    float* __restrict__ y)         // (N, C, S)
{
    __shared__ __align__(16) float Qs[16][100];  // [s-row][d]
    __shared__ __align__(16) float Kt[16][100];  // [l][d]
    __shared__ float Vs[96][17];                 // [d][l], v * tm^3
    __shared__ float Es[16][17];                 // [s-row][l], exp(coef)
    __shared__ float tms[16];
    __shared__ float ims[16];
    __shared__ float dnS[16];

    const int n = blockIdx.z, h = blockIdx.y;
    const int s0 = blockIdx.x * 16;
    const int tid = threadIdx.x;
    const int row = tid >> 4;      // s-row this thread handles
    const int lx  = tid & 15;      // l within chunk (score) / d-group (PV)
    const float scale = 0.10206207261596577f;  // 1/sqrt(96)

    // Q tile (16 x 96) and im_mask
    const long qbase = ((long)n * C_DIM + h * D_DIM) * S_DIM;
    #pragma unroll
    for (int i = 0; i < 6; i++) {
        int idx = tid + i * 256;
        int rr = idx & 15, dd = idx >> 4;
        Qs[rr][dd] = q[qbase + (long)dd * S_DIM + s0 + rr];
    }
    if (tid < 16) ims[tid] = imask[(long)n * S_DIM + s0 + tid];

    float acc[6] = {0.f, 0.f, 0.f, 0.f, 0.f, 0.f};
    float dn = 0.0f;

    const long kvbase = ((long)n * C_DIM + h * D_DIM) * L_DIM;
    const long projbase = (((long)n * H_DIM + h) * S_DIM + s0) * L_DIM;

    for (int l0 = 0; l0 < L_DIM; l0 += 16) {
        __syncthreads();   // previous iteration done reading Kt/Vs/Es/tms
        if (tid < 16) tms[tid] = tmask[(long)n * L_DIM + l0 + tid];
        #pragma unroll
        for (int i = 0; i < 6; i++) {
            int idx = tid + i * 256;
            int ll = idx & 15, dd = idx >> 4;
            Kt[ll][dd] = k[kvbase + (long)dd * L_DIM + l0 + ll];
            float t = tmask[(long)n * L_DIM + l0 + ll];
            Vs[dd][ll] = v[kvbase + (long)dd * L_DIM + l0 + ll] * t * t * t;
        }
        __syncthreads();

        // ---- score phase: thread -> (row, l = lx)
        float dot = 0.0f;
        #pragma unroll
        for (int d4 = 0; d4 < 96; d4 += 4) {
            float4 qa = *(const float4*)&Qs[row][d4];
            float4 kb = *(const float4*)&Kt[lx][d4];
            dot = fmaf(qa.x, kb.x, dot);
            dot = fmaf(qa.y, kb.y, dot);
            dot = fmaf(qa.z, kb.z, dot);
            dot = fmaf(qa.w, kb.w, dot);
        }
        float coef = dot * scale * ims[row];
        proj[projbase + (long)row * L_DIM + l0 + lx] = coef * tms[lx];
        Es[row][lx] = expf(coef);
        __syncthreads();

        // ---- PV phase: thread -> (row, d = lx*6 .. lx*6+5)
        float er[16];
        #pragma unroll
        for (int l = 0; l < 16; l++) er[l] = Es[row][l];
        if (lx == 0) {
            float s = 0.0f;
            #pragma unroll
            for (int l = 0; l < 16; l++) s = fmaf(er[l], tms[l], s);
            dn += s;
        }
        #pragma unroll
        for (int j = 0; j < 6; j++) {
            int dd = lx * 6 + j;
            float a = 0.0f;
            #pragma unroll
            for (int l = 0; l < 16; l++) a = fmaf(er[l], Vs[dd][l], a);
            acc[j] += a;
        }
    }

    if (lx == 0) dnS[row] = dn + 1e-6f;
    __syncthreads();
    const float dinv = 1.0f / dnS[row];
    #pragma unroll
    for (int j = 0; j < 6; j++) {
        int dd = lx * 6 + j;
        long xi = ((long)n * C_DIM + h * D_DIM + dd) * S_DIM + s0 + row;
        y[xi] = x[xi] + acc[j] * dinv;
    }
}

// ---------------------------------------------------------------------------
extern "C" void kernel_launch(void* const* d_in, const int* in_sizes, int n_in,
                              void* d_out, int out_size, void* d_ws, size_t ws_size,
                              hipStream_t stream)
{
    const float* x   = (const float*)d_in[0];  // (2,768,4096)
    const float* x_t = (const float*)d_in[1];  // (2,384,1024)
    const float* tm  = (const float*)d_in[2];  // (2,1024)
    const float* im  = (const float*)d_in[3];  // (2,4096)
    const float* Wv  = (const float*)d_in[4];  // (768,384)
    const float* Wk  = (const float*)d_in[5];  // (768,384)
    const float* Wq  = (const float*)d_in[6];  // (768,768)
    const float* W1  = (const float*)d_in[7];  // (1536,768)
    const float* W2  = (const float*)d_in[8];  // (768,1536)

    float* out_x = (float*)d_out;                                  // (2,768,4096)
    float* proj  = out_x + (long)N_BATCH * C_DIM * S_DIM;          // (2,8,4096,1024)

    float* ws   = (float*)d_ws;
    float* q    = ws;                                   // 2*768*4096 = 6291456
    float* vbuf = q    + (long)N_BATCH * C_DIM * S_DIM; // 2*768*1024 = 1572864
    float* kbuf = vbuf + (long)N_BATCH * C_DIM * L_DIM;
    float* y    = kbuf + (long)N_BATCH * C_DIM * L_DIM; // 6291456
    float* hmid = y    + (long)N_BATCH * C_DIM * S_DIM; // 2*1536*4096 = 12582912

    dim3 blk(256);

    // v = Wv @ x_t, k = Wk @ x_t   (M=768, N=1024, K=384)
    gemm_f32<false, false><<<dim3(16, 12, 2), blk, 0, stream>>>(
        Wv, x_t, nullptr, vbuf, C_DIM, L_DIM, TC_DIM,
        (long)TC_DIM * L_DIM, (long)C_DIM * L_DIM);
    gemm_f32<false, false><<<dim3(16, 12, 2), blk, 0, stream>>>(
        Wk, x_t, nullptr, kbuf, C_DIM, L_DIM, TC_DIM,
        (long)TC_DIM * L_DIM, (long)C_DIM * L_DIM);

    // q = Wq @ x   (M=768, N=4096, K=768)
    gemm_f32<false, false><<<dim3(64, 12, 2), blk, 0, stream>>>(
        Wq, x, nullptr, q, C_DIM, S_DIM, C_DIM,
        (long)C_DIM * S_DIM, (long)C_DIM * S_DIM);

    // fused attention -> proj (d_out) and y (= x + x_p)
    attn_fused<<<dim3(S_DIM / 16, H_DIM, N_BATCH), blk, 0, stream>>>(
        q, kbuf, vbuf, x, tm, im, proj, y);

    // hmid = relu(W1 @ y)   (M=1536, N=4096, K=768)
    gemm_f32<true, false><<<dim3(64, 24, 2), blk, 0, stream>>>(
        W1, y, nullptr, hmid, F_DIM, S_DIM, C_DIM,
        (long)C_DIM * S_DIM, (long)F_DIM * S_DIM);

    // out_x = x + W2 @ hmid   (M=768, N=4096, K=1536)
    gemm_f32<false, true><<<dim3(64, 12, 2), blk, 0, stream>>>(
        W2, hmid, x, out_x, C_DIM, S_DIM, F_DIM,
        (long)F_DIM * S_DIM, (long)C_DIM * S_DIM);
}

// Round 2
// 550.862 us; speedup vs baseline: 3.7463x; 3.7463x over previous
//
#include <hip/hip_runtime.h>
#include <hip/hip_bf16.h>

#define N_BATCH 2
#define C_DIM   768
#define S_DIM   4096
#define L_DIM   1024
#define H_DIM   8
#define D_DIM   96
#define TC_DIM  384
#define F_DIM   1536

typedef short  s16x8 __attribute__((ext_vector_type(8)));
typedef ushort u16x4 __attribute__((ext_vector_type(4)));
typedef float  f32x4 __attribute__((ext_vector_type(4)));

__device__ inline ushort f2bf(float f) {
    uint u = __builtin_bit_cast(uint, f);
    u += 0x7fffu + ((u >> 16) & 1u);
    return (ushort)(u >> 16);
}
__device__ inline float bf2f(ushort u) {
    return __builtin_bit_cast(float, ((uint)u) << 16);
}
__device__ inline f32x4 mfma16(s16x8 a, s16x8 b, f32x4 c) {
    return __builtin_amdgcn_mfma_f32_16x16x32_bf16(a, b, c, 0, 0, 0);
}

// ---------------------------------------------------------------------------
// flat f32 -> bf16 convert (4 elements/thread)
// ---------------------------------------------------------------------------
__global__ __launch_bounds__(256) void cvt_bf16(const float* __restrict__ in,
                                                ushort* __restrict__ out, int n4)
{
    int i = blockIdx.x * 256 + threadIdx.x;
    if (i >= n4) return;
    f32x4 v = *(const f32x4*)&in[(long)i * 4];
    u16x4 p;
    p[0] = f2bf(v[0]); p[1] = f2bf(v[1]); p[2] = f2bf(v[2]); p[3] = f2bf(v[3]);
    *(u16x4*)&out[(long)i * 4] = p;
}

// ---------------------------------------------------------------------------
// transpose + convert: in f32 (B, R, Cl) -> out bf16 (B, Cl, R)
// ---------------------------------------------------------------------------
__global__ __launch_bounds__(256) void transpose_cvt(const float* __restrict__ in,
                                                     ushort* __restrict__ out,
                                                     int R, int Cl)
{
    __shared__ float T[32][33];
    const int b = blockIdx.z;
    const float* ib = in + (long)b * R * Cl;
    ushort* ob = out + (long)b * R * Cl;
    const int c0 = blockIdx.x * 32, r0 = blockIdx.y * 32;
    const int tx = threadIdx.x & 31, ty = threadIdx.x >> 5;
    #pragma unroll
    for (int i = 0; i < 4; ++i)
        T[ty + i * 8][tx] = ib[(long)(r0 + ty + i * 8) * Cl + c0 + tx];
    __syncthreads();
    #pragma unroll
    for (int i = 0; i < 4; ++i)
        ob[(long)(c0 + ty + i * 8) * R + r0 + tx] = f2bf(T[tx][ty + i * 8]);
}

// ---------------------------------------------------------------------------
// bf16 MFMA GEMM: D[r][m] = sum_k Act[b][r][k] * W[m][k]
// Act: (B, R, K) bf16 row-major (k contiguous). W: (M, K) bf16 (k contiguous).
// NAT (TR=0): Out[b][r][m] bf16.  TR=1: Out[b][m][r] (bf16 or f32, +X f32).
// 128x128 tile, BK=32, 256 threads = 4 waves (2x2), wave tile 64x64.
// ---------------------------------------------------------------------------
template<bool RELU, bool TR, bool ADDX, bool OUTBF>
__global__ __launch_bounds__(256) void gemm_mfma(
    const ushort* __restrict__ Act, const ushort* __restrict__ W,
    const float* __restrict__ X, void* __restrict__ OutP,
    int R, int M, int K)
{
    __shared__ __align__(16) ushort As[128][56];
    __shared__ __align__(16) ushort Bs[128][56];
    const int b = blockIdx.z;
    const int r0 = blockIdx.x * 128, m0 = blockIdx.y * 128;
    const int tid = threadIdx.x;
    const int lane = tid & 63, wave = tid >> 6;
    const int wr = wave >> 1, wc = wave & 1;
    const int ln = lane & 15, lk = lane >> 4;
    const long actB = (long)b * R * K;

    const f32x4 fz = {0.f, 0.f, 0.f, 0.f};
    f32x4 acc[4][4];
    #pragma unroll
    for (int i = 0; i < 4; ++i)
        #pragma unroll
        for (int j = 0; j < 4; ++j) acc[i][j] = fz;

    for (int k0 = 0; k0 < K; k0 += 32) {
        #pragma unroll
        for (int it = 0; it < 2; ++it) {
            int idx = tid + it * 256;
            int rr = idx >> 2, kk = (idx & 3) * 8;
            *(s16x8*)&As[rr][kk] =
                *(const s16x8*)&Act[actB + (long)(r0 + rr) * K + k0 + kk];
            *(s16x8*)&Bs[rr][kk] =
                *(const s16x8*)&W[(long)(m0 + rr) * K + k0 + kk];
        }
        __syncthreads();
        s16x8 af[4], bw[4];
        #pragma unroll
        for (int f = 0; f < 4; ++f) {
            af[f] = *(const s16x8*)&As[wr * 64 + f * 16 + ln][lk * 8];
            bw[f] = *(const s16x8*)&Bs[wc * 64 + f * 16 + ln][lk * 8];
        }
        #pragma unroll
        for (int fi = 0; fi < 4; ++fi)
            #pragma unroll
            for (int fj = 0; fj < 4; ++fj)
                acc[fi][fj] = mfma16(af[fi], bw[fj], acc[fi][fj]);
        __syncthreads();
    }

    if (!TR) {
        ushort* o = (ushort*)OutP + (long)b * R * M;
        #pragma unroll
        for (int fi = 0; fi < 4; ++fi) {
            #pragma unroll
            for (int reg = 0; reg < 4; ++reg) {
                long r = r0 + wr * 64 + fi * 16 + lk * 4 + reg;
                #pragma unroll
                for (int fj = 0; fj < 4; ++fj) {
                    int m = m0 + wc * 64 + fj * 16 + ln;
                    float v = acc[fi][fj][reg];
                    if (RELU) v = fmaxf(v, 0.f);
                    o[r * M + m] = f2bf(v);
                }
            }
        }
    } else {
        #pragma unroll
        for (int fi = 0; fi < 4; ++fi) {
            #pragma unroll
            for (int fj = 0; fj < 4; ++fj) {
                int m = m0 + wc * 64 + fj * 16 + ln;
                long r = r0 + wr * 64 + fi * 16 + lk * 4;
                long base = (long)b * M * R + (long)m * R + r;
                if (OUTBF) {
                    u16x4 p;
                    #pragma unroll
                    for (int reg = 0; reg < 4; ++reg) {
                        float v = acc[fi][fj][reg];
                        if (RELU) v = fmaxf(v, 0.f);
                        p[reg] = f2bf(v);
                    }
                    *(u16x4*)((ushort*)OutP + base) = p;
                } else {
                    f32x4 v = acc[fi][fj];
                    if (ADDX) {
                        f32x4 xv = *(const f32x4*)&X[base];
                        v = v + xv;
                    }
                    *(f32x4*)((float*)OutP + base) = v;
                }
            }
        }
    }
}

// ---------------------------------------------------------------------------
// MFMA attention. Block = (n, h) x 64 s-rows; 4 waves, wave owns 16 s-rows.
//   coef[s,l] = (q·k)/sqrt(96) * im[s];  proj = coef*tm
//   dn[s] = sum_l exp(coef)*tm;  x_p[s,d] = sum_l exp(coef)*tm^3*v[d,l]/dn
//   y_t[s][c] = x[c][s] + x_p   (bf16)
// ---------------------------------------------------------------------------
__global__ __launch_bounds__(256) void attn_mfma(
    const ushort* __restrict__ qt,    // (N, S, 768)
    const ushort* __restrict__ kt,    // (N, L, 768)
    const ushort* __restrict__ vb,    // (N, 768, L)
    const float* __restrict__ x,      // (N, 768, S)
    const float* __restrict__ tmask,  // (N, L)
    const float* __restrict__ imask,  // (N, S)
    float* __restrict__ proj,         // (N, 8, S, L)
    ushort* __restrict__ yt)          // (N, S, 768)
{
    __shared__ __align__(16) char smem[37888];
    ushort (*Qs)[104] = (ushort(*)[104])(smem);           // [64][104]
    ushort (*Ks)[104] = (ushort(*)[104])(smem + 13312);   // [32][104]
    ushort (*Vs)[56]  = (ushort(*)[56]) (smem + 19968);   // [96][56]
    ushort (*Es)[56]  = (ushort(*)[56]) (smem + 30720);   // [64][56]
    float  (*Ys)[100] = (float(*)[100])(smem);            // [64][100] alias

    const int n = blockIdx.z, h = blockIdx.y, s0 = blockIdx.x * 64;
    const int tid = threadIdx.x, lane = tid & 63, w = tid >> 6;
    const int ln = lane & 15, lk = lane >> 4;
    const float scale = 0.10206207261596577f;  // 1/sqrt(96)

    // stage Q tile (64 x 96), 12 x short8 per row
    const ushort* qrow = qt + ((long)n * S_DIM + s0) * C_DIM + h * D_DIM;
    for (int i = tid; i < 768; i += 256) {
        int sr = i / 12, jj = (i % 12) * 8;
        *(s16x8*)&Qs[sr][jj] = *(const s16x8*)&qrow[(long)sr * C_DIM + jj];
    }
    float imr[4];
    #pragma unroll
    for (int reg = 0; reg < 4; ++reg)
        imr[reg] = imask[(long)n * S_DIM + s0 + w * 16 + lk * 4 + reg];

    const f32x4 fz = {0.f, 0.f, 0.f, 0.f};
    f32x4 pv[6];
    #pragma unroll
    for (int j = 0; j < 6; ++j) pv[j] = fz;
    float dn[4] = {0.f, 0.f, 0.f, 0.f};

    const ushort* ktb = kt + (long)n * L_DIM * C_DIM + h * D_DIM;
    const ushort* vbb = vb + ((long)n * C_DIM + h * D_DIM) * L_DIM;
    const float*  tmb = tmask + (long)n * L_DIM;
    const long projb = (((long)n * H_DIM + h) * S_DIM + s0 + w * 16) * L_DIM;

    for (int l0 = 0; l0 < L_DIM; l0 += 32) {
        __syncthreads();   // prev chunk's Ks/Vs reads done
        // stage K tile (32 x 96)
        for (int i = tid; i < 384; i += 256) {
            int ll = i / 12, jj = (i % 12) * 8;
            *(s16x8*)&Ks[ll][jj] =
                *(const s16x8*)&ktb[(long)(l0 + ll) * C_DIM + jj];
        }
        // stage V tile (96 x 32) with tm^3
        for (int i = tid; i < 384; i += 256) {
            int d = i >> 2, jj = (i & 3) * 8;
            s16x8 vv = *(const s16x8*)&vbb[(long)d * L_DIM + l0 + jj];
            ushort ov[8];
            #pragma unroll
            for (int e = 0; e < 8; ++e) {
                float t = tmb[l0 + jj + e];
                ov[e] = f2bf(bf2f((ushort)vv[e]) * t * t * t);
            }
            *(s16x8*)&Vs[d][jj] = *(s16x8*)ov;
        }
        __syncthreads();

        // ---- scores: D[s(16) x l(16)] x2, K-dim d=96 in 3 steps
        s16x8 aq[3];
        #pragma unroll
        for (int kc = 0; kc < 3; ++kc)
            aq[kc] = *(const s16x8*)&Qs[w * 16 + ln][kc * 32 + lk * 8];
        f32x4 sc[2];
        sc[0] = fz; sc[1] = fz;
        #pragma unroll
        for (int sub = 0; sub < 2; ++sub)
            #pragma unroll
            for (int kc = 0; kc < 3; ++kc) {
                s16x8 bk = *(const s16x8*)&Ks[sub * 16 + ln][kc * 32 + lk * 8];
                sc[sub] = mfma16(aq[kc], bk, sc[sub]);
            }

        #pragma unroll
        for (int sub = 0; sub < 2; ++sub) {
            float tmc = tmb[l0 + sub * 16 + ln];
            #pragma unroll
            for (int reg = 0; reg < 4; ++reg) {
                float coef = sc[sub][reg] * scale * imr[reg];
                proj[projb + (long)(lk * 4 + reg) * L_DIM + l0 + sub * 16 + ln] =
                    coef * tmc;
                float e = __expf(coef);
                dn[reg] += e * tmc;
                Es[w * 16 + lk * 4 + reg][sub * 16 + ln] = f2bf(e);
            }
        }
        asm volatile("s_waitcnt lgkmcnt(0)");
        __builtin_amdgcn_sched_barrier(0);

        // ---- PV: D[s(16) x d(16)] x6, K-dim l=32 in 1 step
        s16x8 pe = *(const s16x8*)&Es[w * 16 + ln][lk * 8];
        #pragma unroll
        for (int fj = 0; fj < 6; ++fj) {
            s16x8 pb = *(const s16x8*)&Vs[fj * 16 + ln][lk * 8];
            pv[fj] = mfma16(pe, pb, pv[fj]);
        }
    }

    // reduce dn across the 16 lanes of each row-group
    #pragma unroll
    for (int m = 1; m < 16; m <<= 1)
        #pragma unroll
        for (int reg = 0; reg < 4; ++reg)
            dn[reg] += __shfl_xor(dn[reg], m, 64);
    float di[4];
    #pragma unroll
    for (int reg = 0; reg < 4; ++reg) di[reg] = 1.f / (dn[reg] + 1e-6f);

    // epilogue: y = x + x_p, transposed to (S, C) bf16 via LDS
    __syncthreads();   // done with Qs/Ks/Vs (Ys aliases them)
    const float* xb = x + ((long)n * C_DIM + h * D_DIM) * S_DIM;
    #pragma unroll
    for (int fj = 0; fj < 6; ++fj) {
        int d = fj * 16 + ln;
        f32x4 xv = *(const f32x4*)&xb[(long)d * S_DIM + s0 + w * 16 + lk * 4];
        #pragma unroll
        for (int reg = 0; reg < 4; ++reg)
            Ys[w * 16 + lk * 4 + reg][d] = pv[fj][reg] * di[reg] + xv[reg];
    }
    asm volatile("s_waitcnt lgkmcnt(0)");
    __builtin_amdgcn_sched_barrier(0);

    ushort* yrow = yt + ((long)n * S_DIM + s0 + w * 16) * C_DIM + h * D_DIM;
    for (int i = lane; i < 384; i += 64) {   // 16 rows x 24 float4
        int row = i / 24, j4 = (i % 24) * 4;
        f32x4 v = *(const f32x4*)&Ys[w * 16 + row][j4];
        u16x4 p;
        p[0] = f2bf(v[0]); p[1] = f2bf(v[1]); p[2] = f2bf(v[2]); p[3] = f2bf(v[3]);
        *(u16x4*)&yrow[(long)row * C_DIM + j4] = p;
    }
}

// ---------------------------------------------------------------------------
extern "C" void kernel_launch(void* const* d_in, const int* in_sizes, int n_in,
                              void* d_out, int out_size, void* d_ws, size_t ws_size,
                              hipStream_t stream)
{
    const float* x   = (const float*)d_in[0];
    const float* x_t = (const float*)d_in[1];
    const float* tm  = (const float*)d_in[2];
    const float* im  = (const float*)d_in[3];
    const float* Wv  = (const float*)d_in[4];
    const float* Wk  = (const float*)d_in[5];
    const float* Wq  = (const float*)d_in[6];
    const float* W1  = (const float*)d_in[7];
    const float* W2  = (const float*)d_in[8];

    float* out_x = (float*)d_out;
    float* proj  = out_x + (long)N_BATCH * C_DIM * S_DIM;

    char* p = (char*)d_ws;
    ushort* x_T   = (ushort*)p; p += (long)N_BATCH * S_DIM * C_DIM * 2;   // (N,S,C)
    ushort* xt_T  = (ushort*)p; p += (long)N_BATCH * L_DIM * TC_DIM * 2;  // (N,L,TC)
    ushort* q_t   = (ushort*)p; p += (long)N_BATCH * S_DIM * C_DIM * 2;   // (N,S,C)
    ushort* k_t   = (ushort*)p; p += (long)N_BATCH * L_DIM * C_DIM * 2;   // (N,L,C)
    ushort* v_bf  = (ushort*)p; p += (long)N_BATCH * C_DIM * L_DIM * 2;   // (N,C,L)
    ushort* y_t   = (ushort*)p; p += (long)N_BATCH * S_DIM * C_DIM * 2;   // (N,S,C)
    ushort* h_t   = (ushort*)p; p += (long)N_BATCH * S_DIM * F_DIM * 2;   // (N,S,F)
    ushort* wv_b  = (ushort*)p; p += (long)C_DIM * TC_DIM * 2;
    ushort* wk_b  = (ushort*)p; p += (long)C_DIM * TC_DIM * 2;
    ushort* wq_b  = (ushort*)p; p += (long)C_DIM * C_DIM * 2;
    ushort* w1_b  = (ushort*)p; p += (long)F_DIM * C_DIM * 2;
    ushort* w2_b  = (ushort*)p; p += (long)C_DIM * F_DIM * 2;

    dim3 blk(256);

    // weight conversions
    cvt_bf16<<<dim3(C_DIM * TC_DIM / 4 / 256), blk, 0, stream>>>(Wv, wv_b, C_DIM * TC_DIM / 4);
    cvt_bf16<<<dim3(C_DIM * TC_DIM / 4 / 256), blk, 0, stream>>>(Wk, wk_b, C_DIM * TC_DIM / 4);
    cvt_bf16<<<dim3(C_DIM * C_DIM  / 4 / 256), blk, 0, stream>>>(Wq, wq_b, C_DIM * C_DIM / 4);
    cvt_bf16<<<dim3(F_DIM * C_DIM  / 4 / 256), blk, 0, stream>>>(W1, w1_b, F_DIM * C_DIM / 4);
    cvt_bf16<<<dim3(C_DIM * F_DIM  / 4 / 256), blk, 0, stream>>>(W2, w2_b, C_DIM * F_DIM / 4);

    // activation transposes: x (N,C,S)->(N,S,C); x_t (N,TC,L)->(N,L,TC)
    transpose_cvt<<<dim3(S_DIM / 32, C_DIM / 32, N_BATCH), blk, 0, stream>>>(x, x_T, C_DIM, S_DIM);
    transpose_cvt<<<dim3(L_DIM / 32, TC_DIM / 32, N_BATCH), blk, 0, stream>>>(x_t, xt_T, TC_DIM, L_DIM);

    // q_t = x_T @ Wq^T  (R=S, M=C, K=C) -> NAT bf16
    gemm_mfma<false, false, false, true><<<dim3(S_DIM / 128, C_DIM / 128, N_BATCH), blk, 0, stream>>>(
        x_T, wq_b, nullptr, q_t, S_DIM, C_DIM, C_DIM);
    // k_t = xt_T @ Wk^T (R=L, M=C, K=TC) -> NAT bf16
    gemm_mfma<false, false, false, true><<<dim3(L_DIM / 128, C_DIM / 128, N_BATCH), blk, 0, stream>>>(
        xt_T, wk_b, nullptr, k_t, L_DIM, C_DIM, TC_DIM);
    // v_bf = (xt_T @ Wv^T)^T (R=L, M=C, K=TC) -> TR bf16 (C, L)
    gemm_mfma<false, true, false, true><<<dim3(L_DIM / 128, C_DIM / 128, N_BATCH), blk, 0, stream>>>(
        xt_T, wv_b, nullptr, v_bf, L_DIM, C_DIM, TC_DIM);

    // attention -> proj (f32, d_out) and y_t (bf16)
    attn_mfma<<<dim3(S_DIM / 64, H_DIM, N_BATCH), blk, 0, stream>>>(
        q_t, k_t, v_bf, x, tm, im, proj, y_t);

    // h_t = relu(y_t @ W1^T) (R=S, M=F, K=C) -> NAT bf16
    gemm_mfma<true, false, false, true><<<dim3(S_DIM / 128, F_DIM / 128, N_BATCH), blk, 0, stream>>>(
        y_t, w1_b, nullptr, h_t, S_DIM, F_DIM, C_DIM);
    // out_x = x + (h_t @ W2^T)^T (R=S, M=C, K=F) -> TR f32 + X
    gemm_mfma<false, true, true, false><<<dim3(S_DIM / 128, C_DIM / 128, N_BATCH), blk, 0, stream>>>(
        h_t, w2_b, x, out_x, S_DIM, C_DIM, F_DIM);
}